// Round 12
// baseline (1241.095 us; speedup 1.0000x reference)
//
#include <hip/hip_runtime.h>

// Fused windowed multi-head attention for MI355X (gfx950).
// B=8192 windows, N=49 tokens, C=192, H=6 heads, HD=32.
// Inputs/outputs are FP32 (per reference); mask int32. Interior compute bf16 MFMA.
//
// Structure (v11): PERSISTENT blocks: 1024 blocks x 384 threads (6 waves, one
// per head), each block loops over WPB=8 consecutive windows. Double-buffered
// x tile AND O tile in LDS -> ONE barrier per window; next-window global
// loads issued after the QKV collapse (acc registers dead) so their HBM
// latency hides under softmax+PV; LDS stage-writes land before the barrier.
// A sched_barrier(0) pins the load issue below the collapse -- v6's failure
// was the compiler hoisting/holding 29 stage registers across the high-
// pressure QKV phase (spill cliff: FETCH 154->1113 MB).
//
// Per-window phases (numerics identical to v10, bit-exact canonical absmax):
//   phase 2: merged QKV GEMM from xbuf[c] -- q,k swapped mfma(W,X) ->
//            Q^T/K^T C-layout; v normal. Collapse: qf/kf via NATURAL-order
//            quad-shuffle xpose (bit-exact S; v8 proved reordered QK^T flips
//            P roundings -> fail), vf dual-packed in registers (v9-verified).
//   [stage issue: 7 float4 + mask loads for window i+1]
//   phase 4+5 per q-tile: S=mfma32(kf,qf); masked softmax (2 shfl_xor);
//            pf=cvt8; O=mfma32(pf,vf); O slice -> obuf[c].
//   [stage write: held regs -> xbuf[c^1] bf16 + mbias[c^1]]
//   [wpj fragment preload -- hides L2 latency under barrier]
//   barrier  (O visible; staged x visible; xbuf[c] reads done 1 iter ago)
//   phase 6: projection GEMM from obuf[c] + bias, fp32 stores (drain under
//            next window's compute).
//
// Why: v10's counters show issue occupies ~4% of block time; no pipe >24%;
// 1 WG/CU always. The time is serial per-block pipeline (dispatch, stage
// latency, barriers, drain) x 32 sequential blocks/CU. v11 amortizes
// dispatch 8x, halves barriers, and overlaps stage/drain with compute.
//
// Weights repacked each call fp32 -> bf16 in B-fragment-contiguous layout:
// wp[(kt*COLS + col)*32 + kk] = w[(kt*32+kk)*COLS + col].

typedef __attribute__((ext_vector_type(8))) short short8;
typedef __attribute__((ext_vector_type(4))) float f32x4;

#define SCALE 0.17677669529663687f   // 32^-0.5
#define WPB   8                      // windows per block

__device__ __forceinline__ unsigned short f2bf(float x) {
    union { float f; unsigned int i; } v; v.f = x;
    return (unsigned short)((v.i + 0x7FFFu + ((v.i >> 16) & 1u)) >> 16);
}

// packed f32x2 -> bf16x2 (RNE), 1 instr
__device__ __forceinline__ unsigned int pkbf(float lo, float hi) {
    unsigned int r;
    asm("v_cvt_pk_bf16_f32 %0, %1, %2" : "=v"(r) : "v"(lo), "v"(hi));
    return r;
}

// two C-layout f32x4 sub-tiles -> one dual-packed K=32 bf16 fragment
__device__ __forceinline__ short8 cvt8(f32x4 lo, f32x4 hi) {
    union { short8 s; unsigned int u[4]; } r;
    r.u[0] = pkbf(lo[0], lo[1]);
    r.u[1] = pkbf(lo[2], lo[3]);
    r.u[2] = pkbf(hi[0], hi[1]);
    r.u[3] = pkbf(hi[2], hi[3]);
    return r.s;
}

__device__ __forceinline__ f32x4 addb(f32x4 v, float b) {
    v[0] += b; v[1] += b; v[2] += b; v[3] += b;
    return v;
}

// C-layout pair (two 16-row tiles) -> NATURAL-order A/B MFMA fragment.
// dst lane (quad,l16) elem e from src lane ((quad&1)*2+(e>>2))*16+l16,
// tile selected by quad>>1.
__device__ __forceinline__ short8 xpose(f32x4 tlo, f32x4 thi, int srcA, bool hi) {
    unsigned int pl0 = pkbf(tlo[0], tlo[1]);
    unsigned int pl1 = pkbf(tlo[2], tlo[3]);
    unsigned int ph0 = pkbf(thi[0], thi[1]);
    unsigned int ph1 = pkbf(thi[2], thi[3]);
    unsigned int a0 = (unsigned int)__shfl((int)pl0, srcA);
    unsigned int b0 = (unsigned int)__shfl((int)ph0, srcA);
    unsigned int a1 = (unsigned int)__shfl((int)pl1, srcA);
    unsigned int b1 = (unsigned int)__shfl((int)ph1, srcA);
    unsigned int a2 = (unsigned int)__shfl((int)pl0, srcA + 16);
    unsigned int b2 = (unsigned int)__shfl((int)ph0, srcA + 16);
    unsigned int a3 = (unsigned int)__shfl((int)pl1, srcA + 16);
    unsigned int b3 = (unsigned int)__shfl((int)ph1, srcA + 16);
    union { short8 s8; unsigned int u[4]; } f;
    f.u[0] = hi ? b0 : a0;
    f.u[1] = hi ? b1 : a1;
    f.u[2] = hi ? b2 : a2;
    f.u[3] = hi ? b3 : a3;
    return f.s8;
}

__global__ void repack_kernel(const float* __restrict__ wqkv,
                              const float* __restrict__ wproj,
                              unsigned short* __restrict__ wq_pack,
                              unsigned short* __restrict__ wp_pack) {
    int idx = blockIdx.x * 256 + threadIdx.x;
    if (idx < 6 * 576 * 32) {
        int kk  = idx & 31;
        int col = (idx >> 5) % 576;
        int kt  = idx / (576 * 32);
        wq_pack[idx] = f2bf(wqkv[(kt * 32 + kk) * 576 + col]);
    } else {
        int j = idx - 6 * 576 * 32;
        if (j < 6 * 192 * 32) {
            int kk  = j & 31;
            int col = (j >> 5) % 192;
            int kt  = j / (192 * 32);
            wp_pack[j] = f2bf(wproj[(kt * 32 + kk) * 192 + col]);
        }
    }
}

__global__ __launch_bounds__(384)
void win_attn_kernel(const float* __restrict__ x,
                     const int* __restrict__ mask,
                     const float* __restrict__ bqkv,
                     const float* __restrict__ bproj,
                     const unsigned short* __restrict__ wq,
                     const unsigned short* __restrict__ wpj,
                     float* __restrict__ out) {
    // Double-buffered: xbuf[c] 64x200 bf16 x tile, obuf[c] 64x200 bf16 O tile.
    // One barrier per window covers all cross-buffer hazards (see header).
    __shared__ __align__(16) unsigned short xbuf[2][12800];
    __shared__ __align__(16) unsigned short obuf[2][12800];
    __shared__ __align__(16) float mbias[2][64];

    const int tid  = threadIdx.x;
    const int lane = tid & 63;
    const int h    = tid >> 6;      // wave index == head
    const int quad = lane >> 4;
    const int l16  = lane & 15;
    const int b0   = blockIdx.x * WPB;

    const int  srcA = ((lane & 16) << 1) | l16;   // ((quad&1)*2)*16 + l16
    const bool hiq  = (lane & 32) != 0;           // quad>>1

    int colb[6];
    #pragma unroll
    for (int t = 0; t < 6; ++t) colb[t] = (t >> 1) * 192 + h * 32 + (t & 1) * 16;

    // ---------------- prologue: stage window b0 -> xbuf[0]; zero pads -----
    {
        const float* xb = x + (size_t)b0 * 9408;
        for (int i4 = tid; i4 < 2352; i4 += 384) {
            int flat = i4 * 4;
            int n = flat / 192, c = flat % 192;
            float4 v = *(const float4*)(const void*)&xb[flat];
            uint2 pk;
            pk.x = pkbf(v.x, v.y);
            pk.y = pkbf(v.z, v.w);
            *(uint2*)(void*)&xbuf[0][n * 200 + c] = pk;
        }
        if (tid < 375) {                      // zero rows 49..63, both buffers
            uint4 z = {0u, 0u, 0u, 0u};
            *(uint4*)(void*)&xbuf[0][9800 + tid * 8] = z;
            *(uint4*)(void*)&xbuf[1][9800 + tid * 8] = z;
        }
        if (tid < 64)
            mbias[0][tid] = (tid < 49 && mask[b0 * 49 + tid] != 0) ? 0.0f
                                                                   : -1e30f;
    }
    __syncthreads();

    #pragma unroll 1
    for (int wi = 0; wi < WPB; ++wi) {
        const int  c    = wi & 1;
        const int  b    = b0 + wi;
        const bool more = (wi + 1 < WPB);
        unsigned short* rg = &xbuf[c][0];
        unsigned short* ob = &obuf[c][0];

        // ---------------- phase 2: MERGED QKV GEMM ------------------------
        // t=0..3 (q,k) swapped: acc[t][nt] = Y[token=nt*16+l16][colb[t]+quad*4+r]
        // t=4..5 (v) normal:    acc[t][mt] = V[token=mt*16+quad*4+r][.. +l16]
        f32x4 acc[6][4];
        #pragma unroll
        for (int t = 0; t < 6; ++t)
            #pragma unroll
            for (int mt = 0; mt < 4; ++mt)
                acc[t][mt] = (f32x4){0.f, 0.f, 0.f, 0.f};

        #pragma unroll
        for (int kt = 0; kt < 6; ++kt) {
            short8 af[4];
            #pragma unroll
            for (int mt = 0; mt < 4; ++mt)
                af[mt] = *(const short8*)(const void*)
                         &rg[(mt * 16 + l16) * 200 + kt * 32 + quad * 8];
            #pragma unroll
            for (int t = 0; t < 6; ++t) {
                short8 bw = *(const short8*)(const void*)
                            &wq[(size_t)(kt * 576 + colb[t] + l16) * 32 + quad * 8];
                #pragma unroll
                for (int mt = 0; mt < 4; ++mt) {
                    if (t < 4)
                        acc[t][mt] = __builtin_amdgcn_mfma_f32_16x16x32_bf16(
                                         bw, af[mt], acc[t][mt], 0, 0, 0);
                    else
                        acc[t][mt] = __builtin_amdgcn_mfma_f32_16x16x32_bf16(
                                         af[mt], bw, acc[t][mt], 0, 0, 0);
                }
            }
        }

        // bias + collapse: qf/kf NATURAL order (bit-exact S), vf dual-packed.
        short8 qf[4], kf[4], vf[2][2];
        {
            f32x4 bq0 = *(const f32x4*)(const void*)&bqkv[colb[0] + quad * 4];
            f32x4 bq1 = *(const f32x4*)(const void*)&bqkv[colb[1] + quad * 4];
            f32x4 bk0 = *(const f32x4*)(const void*)&bqkv[colb[2] + quad * 4];
            f32x4 bk1 = *(const f32x4*)(const void*)&bqkv[colb[3] + quad * 4];
            #pragma unroll
            for (int nt = 0; nt < 4; ++nt) {
                qf[nt] = xpose(acc[0][nt] + bq0, acc[1][nt] + bq1, srcA, hiq);
                kf[nt] = xpose(acc[2][nt] + bk0, acc[3][nt] + bk1, srcA, hiq);
            }
            float bv0 = bqkv[colb[4] + l16];
            float bv1 = bqkv[colb[5] + l16];
            #pragma unroll
            for (int j = 0; j < 2; ++j) {
                vf[0][j] = cvt8(addb(acc[4][2 * j], bv0),
                                addb(acc[4][2 * j + 1], bv0));
                vf[1][j] = cvt8(addb(acc[5][2 * j], bv1),
                                addb(acc[5][2 * j + 1], bv1));
            }
        }

        // ---- issue next-window stage loads (acc dead; pinned here so the
        // ~29 held regs overlap only phases 4-5, not the QKV GEMM) ----------
        __builtin_amdgcn_sched_barrier(0);
        float4 st[6];
        float4 st6 = {0.f, 0.f, 0.f, 0.f};
        int mv = 0;
        if (more) {
            const float* xn = x + (size_t)(b + 1) * 9408;
            #pragma unroll
            for (int k = 0; k < 6; ++k)
                st[k] = *(const float4*)(const void*)&xn[(tid + k * 384) * 4];
            if (tid < 48)
                st6 = *(const float4*)(const void*)&xn[(2304 + tid) * 4];
            if (tid < 49)
                mv = mask[(b + 1) * 49 + tid];
        }

        // ---------------- phase 4+5: per q-tile S, softmax, O -------------
        f32x4 mb4[4];
        #pragma unroll
        for (int mt = 0; mt < 4; ++mt)
            mb4[mt] = *(const f32x4*)(const void*)&mbias[c][mt * 16 + quad * 4];

        #pragma unroll
        for (int nt = 0; nt < 4; ++nt) {
            f32x4 sr[4];
            #pragma unroll
            for (int mt = 0; mt < 4; ++mt) {
                sr[mt] = (f32x4){0.f, 0.f, 0.f, 0.f};
                sr[mt] = __builtin_amdgcn_mfma_f32_16x16x32_bf16(
                             kf[mt], qf[nt], sr[mt], 0, 0, 0);
            }
            float pm[4];
            #pragma unroll
            for (int mt = 0; mt < 4; ++mt) {
                #pragma unroll
                for (int r = 0; r < 4; ++r)
                    sr[mt][r] = sr[mt][r] * SCALE + mb4[mt][r];
                pm[mt] = fmaxf(fmaxf(sr[mt][0], sr[mt][1]),
                               fmaxf(sr[mt][2], sr[mt][3]));
            }
            float mx = fmaxf(fmaxf(pm[0], pm[1]), fmaxf(pm[2], pm[3]));
            mx = fmaxf(mx, __shfl_xor(mx, 16));
            mx = fmaxf(mx, __shfl_xor(mx, 32));
            float ps[4];
            #pragma unroll
            for (int mt = 0; mt < 4; ++mt) {
                #pragma unroll
                for (int r = 0; r < 4; ++r)
                    sr[mt][r] = __expf(sr[mt][r] - mx);
                ps[mt] = (sr[mt][0] + sr[mt][1]) + (sr[mt][2] + sr[mt][3]);
            }
            float sum = (ps[0] + ps[1]) + (ps[2] + ps[3]);
            sum += __shfl_xor(sum, 16);
            sum += __shfl_xor(sum, 32);
            float inv = 1.0f / sum;
            #pragma unroll
            for (int mt = 0; mt < 4; ++mt)
                #pragma unroll
                for (int r = 0; r < 4; ++r)
                    sr[mt][r] *= inv;

            short8 pf[2];
            pf[0] = cvt8(sr[0], sr[1]);
            pf[1] = cvt8(sr[2], sr[3]);

            f32x4 on[2];
            #pragma unroll
            for (int t = 0; t < 2; ++t)
                on[t] = (f32x4){0.f, 0.f, 0.f, 0.f};
            #pragma unroll
            for (int j = 0; j < 2; ++j)
                #pragma unroll
                for (int t = 0; t < 2; ++t)
                    on[t] = __builtin_amdgcn_mfma_f32_16x16x32_bf16(
                                pf[j], vf[t][j], on[t], 0, 0, 0);

            #pragma unroll
            for (int t = 0; t < 2; ++t)
                #pragma unroll
                for (int r = 0; r < 4; ++r)
                    ob[(nt * 16 + quad * 4 + r) * 200 + h * 32 + t * 16 + l16]
                        = f2bf(on[t][r]);
        }

        // ---- stage writes: held regs -> xbuf[c^1] (st dies here) ---------
        if (more) {
            unsigned short* nb = &xbuf[c ^ 1][0];
            #pragma unroll
            for (int k = 0; k < 6; ++k) {
                int flat = (tid + k * 384) * 4;
                int n = flat / 192, cc = flat % 192;
                uint2 pk;
                pk.x = pkbf(st[k].x, st[k].y);
                pk.y = pkbf(st[k].z, st[k].w);
                *(uint2*)(void*)&nb[n * 200 + cc] = pk;
            }
            if (tid < 48) {
                int flat = (2304 + tid) * 4;
                int n = flat / 192, cc = flat % 192;
                uint2 pk;
                pk.x = pkbf(st6.x, st6.y);
                pk.y = pkbf(st6.z, st6.w);
                *(uint2*)(void*)&nb[n * 200 + cc] = pk;
            }
            if (tid < 64)
                mbias[c ^ 1][tid] = (tid < 49 && mv != 0) ? 0.0f : -1e30f;
        }

        // preload projection-weight fragments (L2 latency under barrier)
        short8 bwp[6][2];
        #pragma unroll
        for (int kt = 0; kt < 6; ++kt)
            #pragma unroll
            for (int nt = 0; nt < 2; ++nt)
                bwp[kt][nt] = *(const short8*)(const void*)
                              &wpj[(size_t)(kt * 192 + h * 32 + nt * 16 + l16) * 32
                                   + quad * 8];

        __syncthreads();   // O + staged x visible; xbuf[c] safe to restage next

        // ---------------- phase 6: projection GEMM + bias + store ---------
        f32x4 po[2][4];
        #pragma unroll
        for (int nt = 0; nt < 2; ++nt)
            #pragma unroll
            for (int mt = 0; mt < 4; ++mt)
                po[nt][mt] = (f32x4){0.f, 0.f, 0.f, 0.f};

        #pragma unroll
        for (int kt = 0; kt < 6; ++kt) {
            short8 ao[4];
            #pragma unroll
            for (int mt = 0; mt < 4; ++mt)
                ao[mt] = *(const short8*)(const void*)
                         &ob[(mt * 16 + l16) * 200 + kt * 32 + quad * 8];
            #pragma unroll
            for (int nt = 0; nt < 2; ++nt)
                #pragma unroll
                for (int mt = 0; mt < 4; ++mt)
                    po[nt][mt] = __builtin_amdgcn_mfma_f32_16x16x32_bf16(
                                     ao[mt], bwp[kt][nt], po[nt][mt], 0, 0, 0);
        }

        #pragma unroll
        for (int nt = 0; nt < 2; ++nt) {
            int col = h * 32 + nt * 16 + l16;
            float bv = bproj[col];
            #pragma unroll
            for (int mt = 0; mt < 4; ++mt)
                #pragma unroll
                for (int r = 0; r < 4; ++r) {
                    int row = mt * 16 + quad * 4 + r;
                    if (row < 49)
                        out[(size_t)b * 9408 + row * 192 + col]
                            = po[nt][mt][r] + bv;
                }
        }
        // stores drain under the next window's compute (no wait here).
    }
}

extern "C" void kernel_launch(void* const* d_in, const int* in_sizes, int n_in,
                              void* d_out, int out_size, void* d_ws, size_t ws_size,
                              hipStream_t stream) {
    const float* x      = (const float*)d_in[0];
    const int*   mask   = (const int*)d_in[1];
    const float* w_qkv  = (const float*)d_in[2];
    const float* b_qkv  = (const float*)d_in[3];
    const float* w_proj = (const float*)d_in[4];
    const float* b_proj = (const float*)d_in[5];
    float*       out    = (float*)d_out;

    unsigned short* wq_pack = (unsigned short*)d_ws;          // 110592 elems
    unsigned short* wp_pack = wq_pack + 110592;               //  36864 elems

    repack_kernel<<<(110592 + 36864 + 255) / 256, 256, 0, stream>>>(
        w_qkv, w_proj, wq_pack, wp_pack);
    win_attn_kernel<<<8192 / WPB, 384, 0, stream>>>(x, mask, b_qkv, b_proj,
                                                    wq_pack, wp_pack, out);
}

// Round 13
// 1045.743 us; speedup vs baseline: 1.1868x; 1.1868x over previous
//
#include <hip/hip_runtime.h>

// Fused windowed multi-head attention for MI355X (gfx950).
// B=8192 windows, N=49 tokens, C=192, H=6 heads, HD=32.
// Inputs/outputs are FP32 (per reference); mask int32. Interior compute bf16 MFMA.
//
// Structure (v12): 1 block per window, 6 waves (one per head). NO x STAGING:
// QKV fragments are read DIRECTLY from global fp32 and converted in-register
// (same RNE cvt_pk as the old staged path -> bit-identical bf16 -> bit-exact
// S). The fragment pattern x[row=mt*16+l16][kt*32+quad*8..+7] is 16 rows x
// 128B = perfectly aligned 64B segments per wave instruction; the window
// (37.6KB) is L2-resident so 6 waves re-read from L2, HBM sees it once.
//
//   phase 2: merged QKV GEMM, af from global (rows>=49 masked to 0);
//            q,k swapped mfma(W,X) -> Q^T/K^T C-layout; v normal.
//            Collapse: qf/kf NATURAL-order xpose (bit-exact S -- v8 proved
//            reordered QK^T fails), vf dual-packed in registers (v9).
//   phase 4+5 per q-tile: S=mfma32(kf,qf); masked softmax (bias computed
//            from per-lane global mask loads -- no mbias LDS); pf=cvt8;
//            O=mfma32(pf,vf); O slice -> LDS obuf.
//   barrier  (the ONLY barrier)
//   phase 6: projection GEMM from obuf (wpj fragments preloaded before the
//            barrier) + bias, fp32 store.
//
// Why: v5 scaling (2x waves+2x windows = 2x time) proves phases saturate a
// shared per-CU throughput resource; accounting says LDS pipe (~15k of 36.4k
// cyc/block) >> matrix (~6.5k). Most LDS traffic was the x fp32->bf16
// staging round-trip. v12 moves x reads to the idle TA/L2 path and deletes
// phase 1 + one barrier. v6/v11 lesson (register prefetch spills at >~120
// total regs) respected: no cross-phase held state beyond v10's.
//
// Weights repacked each call fp32 -> bf16 in B-fragment-contiguous layout:
// wp[(kt*COLS + col)*32 + kk] = w[(kt*32+kk)*COLS + col].

typedef __attribute__((ext_vector_type(8))) short short8;
typedef __attribute__((ext_vector_type(4))) float f32x4;

#define SCALE 0.17677669529663687f   // 32^-0.5

__device__ __forceinline__ unsigned short f2bf(float x) {
    union { float f; unsigned int i; } v; v.f = x;
    return (unsigned short)((v.i + 0x7FFFu + ((v.i >> 16) & 1u)) >> 16);
}

// packed f32x2 -> bf16x2 (RNE), 1 instr
__device__ __forceinline__ unsigned int pkbf(float lo, float hi) {
    unsigned int r;
    asm("v_cvt_pk_bf16_f32 %0, %1, %2" : "=v"(r) : "v"(lo), "v"(hi));
    return r;
}

// 8 consecutive f32 (as two f32x4) -> natural-order bf16x8 fragment word
__device__ __forceinline__ short8 cvt8(f32x4 lo, f32x4 hi) {
    union { short8 s; unsigned int u[4]; } r;
    r.u[0] = pkbf(lo[0], lo[1]);
    r.u[1] = pkbf(lo[2], lo[3]);
    r.u[2] = pkbf(hi[0], hi[1]);
    r.u[3] = pkbf(hi[2], hi[3]);
    return r.s;
}

__device__ __forceinline__ f32x4 addb(f32x4 v, float b) {
    v[0] += b; v[1] += b; v[2] += b; v[3] += b;
    return v;
}

// C-layout pair (two 16-row tiles) -> NATURAL-order A/B MFMA fragment.
// dst lane (quad,l16) elem e from src lane ((quad&1)*2+(e>>2))*16+l16,
// tile selected by quad>>1.
__device__ __forceinline__ short8 xpose(f32x4 tlo, f32x4 thi, int srcA, bool hi) {
    unsigned int pl0 = pkbf(tlo[0], tlo[1]);
    unsigned int pl1 = pkbf(tlo[2], tlo[3]);
    unsigned int ph0 = pkbf(thi[0], thi[1]);
    unsigned int ph1 = pkbf(thi[2], thi[3]);
    unsigned int a0 = (unsigned int)__shfl((int)pl0, srcA);
    unsigned int b0 = (unsigned int)__shfl((int)ph0, srcA);
    unsigned int a1 = (unsigned int)__shfl((int)pl1, srcA);
    unsigned int b1 = (unsigned int)__shfl((int)ph1, srcA);
    unsigned int a2 = (unsigned int)__shfl((int)pl0, srcA + 16);
    unsigned int b2 = (unsigned int)__shfl((int)ph0, srcA + 16);
    unsigned int a3 = (unsigned int)__shfl((int)pl1, srcA + 16);
    unsigned int b3 = (unsigned int)__shfl((int)ph1, srcA + 16);
    union { short8 s8; unsigned int u[4]; } f;
    f.u[0] = hi ? b0 : a0;
    f.u[1] = hi ? b1 : a1;
    f.u[2] = hi ? b2 : a2;
    f.u[3] = hi ? b3 : a3;
    return f.s8;
}

__global__ void repack_kernel(const float* __restrict__ wqkv,
                              const float* __restrict__ wproj,
                              unsigned short* __restrict__ wq_pack,
                              unsigned short* __restrict__ wp_pack) {
    int idx = blockIdx.x * 256 + threadIdx.x;
    if (idx < 6 * 576 * 32) {
        int kk  = idx & 31;
        int col = (idx >> 5) % 576;
        int kt  = idx / (576 * 32);
        wq_pack[idx] = f2bf(wqkv[(kt * 32 + kk) * 576 + col]);
    } else {
        int j = idx - 6 * 576 * 32;
        if (j < 6 * 192 * 32) {
            int kk  = j & 31;
            int col = (j >> 5) % 192;
            int kt  = j / (192 * 32);
            wp_pack[j] = f2bf(wproj[(kt * 32 + kk) * 192 + col]);
        }
    }
}

__global__ __launch_bounds__(384)
void win_attn_kernel(const float* __restrict__ x,
                     const int* __restrict__ mask,
                     const float* __restrict__ bqkv,
                     const float* __restrict__ bproj,
                     const unsigned short* __restrict__ wq,
                     const unsigned short* __restrict__ wpj,
                     float* __restrict__ out) {
    // LDS: only the O tile (64x200 bf16) for the cross-head projection.
    __shared__ __align__(16) unsigned short ob[12800];

    const int b    = blockIdx.x;
    const int tid  = threadIdx.x;
    const int lane = tid & 63;
    const int h    = tid >> 6;      // wave index == head
    const int quad = lane >> 4;
    const int l16  = lane & 15;

    const int  srcA = ((lane & 16) << 1) | l16;   // ((quad&1)*2)*16 + l16
    const bool hiq  = (lane & 32) != 0;           // quad>>1

    int colb[6];
    #pragma unroll
    for (int t = 0; t < 6; ++t) colb[t] = (t >> 1) * 192 + h * 32 + (t & 1) * 16;

    const float* xb = x + (size_t)b * 9408;

    // ---------------- phase 2: merged QKV GEMM (x from global) ------------
    // t=0..3 (q,k) swapped: acc[t][nt] = Y[token=nt*16+l16][colb[t]+quad*4+r]
    // t=4..5 (v) normal:    acc[t][mt] = V[token=mt*16+quad*4+r][..+l16]
    f32x4 acc[6][4];
    #pragma unroll
    for (int t = 0; t < 6; ++t)
        #pragma unroll
        for (int mt = 0; mt < 4; ++mt)
            acc[t][mt] = (f32x4){0.f, 0.f, 0.f, 0.f};

    #pragma unroll
    for (int kt = 0; kt < 6; ++kt) {
        short8 af[4];
        #pragma unroll
        for (int mt = 0; mt < 4; ++mt) {
            int row = mt * 16 + l16;
            f32x4 lo = (f32x4){0.f, 0.f, 0.f, 0.f};
            f32x4 hi = (f32x4){0.f, 0.f, 0.f, 0.f};
            if (row < 49) {
                const float* p = &xb[row * 192 + kt * 32 + quad * 8];
                lo = *(const f32x4*)(const void*)p;
                hi = *(const f32x4*)(const void*)(p + 4);
            }
            af[mt] = cvt8(lo, hi);   // same RNE as staged path: bit-exact
        }
        #pragma unroll
        for (int t = 0; t < 6; ++t) {
            short8 bw = *(const short8*)(const void*)
                        &wq[(size_t)(kt * 576 + colb[t] + l16) * 32 + quad * 8];
            #pragma unroll
            for (int mt = 0; mt < 4; ++mt) {
                if (t < 4)
                    acc[t][mt] = __builtin_amdgcn_mfma_f32_16x16x32_bf16(
                                     bw, af[mt], acc[t][mt], 0, 0, 0);
                else
                    acc[t][mt] = __builtin_amdgcn_mfma_f32_16x16x32_bf16(
                                     af[mt], bw, acc[t][mt], 0, 0, 0);
            }
        }
    }

    // bias + collapse: qf/kf NATURAL order (bit-exact S), vf dual-packed.
    short8 qf[4], kf[4], vf[2][2];
    {
        f32x4 bq0 = *(const f32x4*)(const void*)&bqkv[colb[0] + quad * 4];
        f32x4 bq1 = *(const f32x4*)(const void*)&bqkv[colb[1] + quad * 4];
        f32x4 bk0 = *(const f32x4*)(const void*)&bqkv[colb[2] + quad * 4];
        f32x4 bk1 = *(const f32x4*)(const void*)&bqkv[colb[3] + quad * 4];
        #pragma unroll
        for (int nt = 0; nt < 4; ++nt) {
            qf[nt] = xpose(acc[0][nt] + bq0, acc[1][nt] + bq1, srcA, hiq);
            kf[nt] = xpose(acc[2][nt] + bk0, acc[3][nt] + bk1, srcA, hiq);
        }
        float bv0 = bqkv[colb[4] + l16];
        float bv1 = bqkv[colb[5] + l16];
        #pragma unroll
        for (int j = 0; j < 2; ++j) {
            vf[0][j] = cvt8(addb(acc[4][2 * j], bv0), addb(acc[4][2 * j + 1], bv0));
            vf[1][j] = cvt8(addb(acc[5][2 * j], bv1), addb(acc[5][2 * j + 1], bv1));
        }
    }

    // mask bias per lane (rows mt*16+quad*4+r), direct from global (L2-hot;
    // 1.6MB mask array is L2-resident; no LDS, no barrier)
    f32x4 mb4[4];
    #pragma unroll
    for (int mt = 0; mt < 4; ++mt)
        #pragma unroll
        for (int r = 0; r < 4; ++r) {
            int row = mt * 16 + quad * 4 + r;
            int mv = 0;
            if (row < 49) mv = mask[b * 49 + row];
            mb4[mt][r] = mv ? 0.0f : -1e30f;
        }

    // ---------------- phase 4+5: per q-tile S, softmax, O -----------------
    #pragma unroll
    for (int nt = 0; nt < 4; ++nt) {
        // sr[mt]: lane holds S[q=nt*16+l16][k=mt*16+quad*4+r]
        f32x4 sr[4];
        #pragma unroll
        for (int mt = 0; mt < 4; ++mt) {
            sr[mt] = (f32x4){0.f, 0.f, 0.f, 0.f};
            sr[mt] = __builtin_amdgcn_mfma_f32_16x16x32_bf16(
                         kf[mt], qf[nt], sr[mt], 0, 0, 0);
        }
        float pm[4];
        #pragma unroll
        for (int mt = 0; mt < 4; ++mt) {
            #pragma unroll
            for (int r = 0; r < 4; ++r)
                sr[mt][r] = sr[mt][r] * SCALE + mb4[mt][r];
            pm[mt] = fmaxf(fmaxf(sr[mt][0], sr[mt][1]),
                           fmaxf(sr[mt][2], sr[mt][3]));
        }
        float mx = fmaxf(fmaxf(pm[0], pm[1]), fmaxf(pm[2], pm[3]));
        mx = fmaxf(mx, __shfl_xor(mx, 16));
        mx = fmaxf(mx, __shfl_xor(mx, 32));
        float ps[4];
        #pragma unroll
        for (int mt = 0; mt < 4; ++mt) {
            #pragma unroll
            for (int r = 0; r < 4; ++r)
                sr[mt][r] = __expf(sr[mt][r] - mx);
            ps[mt] = (sr[mt][0] + sr[mt][1]) + (sr[mt][2] + sr[mt][3]);
        }
        float sum = (ps[0] + ps[1]) + (ps[2] + ps[3]);
        sum += __shfl_xor(sum, 16);
        sum += __shfl_xor(sum, 32);
        float inv = 1.0f / sum;
        #pragma unroll
        for (int mt = 0; mt < 4; ++mt)
            #pragma unroll
            for (int r = 0; r < 4; ++r)
                sr[mt][r] *= inv;

        // pf[j]: P A-fragment (m=q=l16), token pair (2j,2j+1) dual-packed
        short8 pf[2];
        pf[0] = cvt8(sr[0], sr[1]);
        pf[1] = cvt8(sr[2], sr[3]);

        // O slice: on[t] (C-layout [q=nt*16+quad*4+r][d=t*16+l16])
        f32x4 on[2];
        #pragma unroll
        for (int t = 0; t < 2; ++t)
            on[t] = (f32x4){0.f, 0.f, 0.f, 0.f};
        #pragma unroll
        for (int j = 0; j < 2; ++j)
            #pragma unroll
            for (int t = 0; t < 2; ++t)
                on[t] = __builtin_amdgcn_mfma_f32_16x16x32_bf16(
                            pf[j], vf[t][j], on[t], 0, 0, 0);

        #pragma unroll
        for (int t = 0; t < 2; ++t)
            #pragma unroll
            for (int r = 0; r < 4; ++r)
                ob[(nt * 16 + quad * 4 + r) * 200 + h * 32 + t * 16 + l16]
                    = f2bf(on[t][r]);
    }

    // preload projection-weight fragments (L2 latency hides under barrier)
    short8 bwp[6][2];
    #pragma unroll
    for (int kt = 0; kt < 6; ++kt)
        #pragma unroll
        for (int nt = 0; nt < 2; ++nt)
            bwp[kt][nt] = *(const short8*)(const void*)
                          &wpj[(size_t)(kt * 192 + h * 32 + nt * 16 + l16) * 32
                               + quad * 8];

    __syncthreads();   // the only barrier: all heads' O visible

    // ---------------- phase 6: projection GEMM + bias + fp32 store -------
    f32x4 po[2][4];
    #pragma unroll
    for (int nt = 0; nt < 2; ++nt)
        #pragma unroll
        for (int mt = 0; mt < 4; ++mt)
            po[nt][mt] = (f32x4){0.f, 0.f, 0.f, 0.f};

    #pragma unroll
    for (int kt = 0; kt < 6; ++kt) {
        short8 ao[4];
        #pragma unroll
        for (int mt = 0; mt < 4; ++mt)
            ao[mt] = *(const short8*)(const void*)
                     &ob[(mt * 16 + l16) * 200 + kt * 32 + quad * 8];
        #pragma unroll
        for (int nt = 0; nt < 2; ++nt)
            #pragma unroll
            for (int mt = 0; mt < 4; ++mt)
                po[nt][mt] = __builtin_amdgcn_mfma_f32_16x16x32_bf16(
                                 ao[mt], bwp[kt][nt], po[nt][mt], 0, 0, 0);
    }

    #pragma unroll
    for (int nt = 0; nt < 2; ++nt) {
        int col = h * 32 + nt * 16 + l16;
        float bv = bproj[col];
        #pragma unroll
        for (int mt = 0; mt < 4; ++mt)
            #pragma unroll
            for (int r = 0; r < 4; ++r) {
                int row = mt * 16 + quad * 4 + r;
                if (row < 49)
                    out[(size_t)b * 9408 + row * 192 + col] = po[nt][mt][r] + bv;
            }
    }
}

extern "C" void kernel_launch(void* const* d_in, const int* in_sizes, int n_in,
                              void* d_out, int out_size, void* d_ws, size_t ws_size,
                              hipStream_t stream) {
    const float* x      = (const float*)d_in[0];
    const int*   mask   = (const int*)d_in[1];
    const float* w_qkv  = (const float*)d_in[2];
    const float* b_qkv  = (const float*)d_in[3];
    const float* w_proj = (const float*)d_in[4];
    const float* b_proj = (const float*)d_in[5];
    float*       out    = (float*)d_out;

    unsigned short* wq_pack = (unsigned short*)d_ws;          // 110592 elems
    unsigned short* wp_pack = wq_pack + 110592;               //  36864 elems

    repack_kernel<<<(110592 + 36864 + 255) / 256, 256, 0, stream>>>(
        w_qkv, w_proj, wq_pack, wp_pack);
    win_attn_kernel<<<8192, 384, 0, stream>>>(x, mask, b_qkv, b_proj,
                                              wq_pack, wp_pack, out);
}